// Round 2
// baseline (495.712 us; speedup 1.0000x reference)
//
#include <hip/hip_runtime.h>

// out = tanh(((LN(z) @ W + b) * scale)/3)*3
// All I/O fp32 (per reference): z (16384,1024), W (1024,4096), out (16384,4096).
// Internal: zn and Wt converted to bf16 for MFMA (no fp32 MFMA on CDNA4).
#define M_DIM 16384
#define K_DIM 1024
#define N_DIM 4096

typedef __bf16 bf16x8 __attribute__((ext_vector_type(8)));
typedef float f32x4 __attribute__((ext_vector_type(4)));

__device__ __forceinline__ unsigned short f2bf(float f) {
    union { float f; unsigned int i; } v; v.f = f;
    unsigned int r = v.i + 0x7fffu + ((v.i >> 16) & 1u);  // round-to-nearest-even
    return (unsigned short)(r >> 16);
}
__device__ __forceinline__ unsigned int pack2(float lo, float hi) {
    return ((unsigned int)f2bf(lo)) | (((unsigned int)f2bf(hi)) << 16);
}

// ---------------- LayerNorm: one wave per row of 1024, fp32 in -> bf16 out ----------------
__global__ __launch_bounds__(256) void ln_kernel(
        const float* __restrict__ z,
        const float* __restrict__ gamma,
        const float* __restrict__ beta,
        unsigned short* __restrict__ zn) {
    const int wave = threadIdx.x >> 6;
    const int lane = threadIdx.x & 63;
    const size_t row = (size_t)blockIdx.x * 4 + wave;
    const float* zr = z + row * K_DIM + lane * 16;

    float x[16];
#pragma unroll
    for (int v = 0; v < 4; v++) {
        float4 p = ((const float4*)zr)[v];
        x[v * 4 + 0] = p.x; x[v * 4 + 1] = p.y; x[v * 4 + 2] = p.z; x[v * 4 + 3] = p.w;
    }

    float s = 0.f, ss = 0.f;
#pragma unroll
    for (int i = 0; i < 16; i++) { s += x[i]; ss += x[i] * x[i]; }
#pragma unroll
    for (int o = 32; o; o >>= 1) { s += __shfl_xor(s, o, 64); ss += __shfl_xor(ss, o, 64); }
    const float mean = s * (1.f / K_DIM);
    const float var = ss * (1.f / K_DIM) - mean * mean;
    const float rstd = rsqrtf(var + 1e-5f);

    float gv[16], bv[16];
    const float* gp = gamma + lane * 16;
    const float* bp = beta + lane * 16;
#pragma unroll
    for (int v = 0; v < 4; v++) {
        float4 g = ((const float4*)gp)[v];
        float4 b = ((const float4*)bp)[v];
        gv[v * 4 + 0] = g.x; gv[v * 4 + 1] = g.y; gv[v * 4 + 2] = g.z; gv[v * 4 + 3] = g.w;
        bv[v * 4 + 0] = b.x; bv[v * 4 + 1] = b.y; bv[v * 4 + 2] = b.z; bv[v * 4 + 3] = b.w;
    }

    float o16[16];
#pragma unroll
    for (int i = 0; i < 16; i++) o16[i] = (x[i] - mean) * rstd * gv[i] + bv[i];

    uint4 q0, q1;
    q0.x = pack2(o16[0], o16[1]);  q0.y = pack2(o16[2], o16[3]);
    q0.z = pack2(o16[4], o16[5]);  q0.w = pack2(o16[6], o16[7]);
    q1.x = pack2(o16[8], o16[9]);  q1.y = pack2(o16[10], o16[11]);
    q1.z = pack2(o16[12], o16[13]); q1.w = pack2(o16[14], o16[15]);
    unsigned short* zo = zn + row * K_DIM + lane * 16;
    *(uint4*)(zo) = q0;
    *(uint4*)(zo + 8) = q1;
}

// ---------------- Transpose+convert W fp32 (K,N) -> Wt bf16 (N,K) ----------------
__global__ __launch_bounds__(256) void tr_kernel(
        const float* __restrict__ W, unsigned short* __restrict__ Wt) {
    __shared__ float t[32][33];
    const int tx = threadIdx.x, ty = threadIdx.y;   // block (32, 8)
    const int n0 = blockIdx.x * 32, k0 = blockIdx.y * 32;
#pragma unroll
    for (int j = 0; j < 32; j += 8)
        t[ty + j][tx] = W[(size_t)(k0 + ty + j) * N_DIM + n0 + tx];
    __syncthreads();
#pragma unroll
    for (int j = 0; j < 32; j += 8)
        Wt[(size_t)(n0 + ty + j) * K_DIM + k0 + tx] = f2bf(t[tx][ty + j]);
}

// ---------------- GEMM: zn (M,K)bf16 @ Wt (N,K)bf16 with fused epilogue, fp32 out ----------------
__device__ __forceinline__ void async_copy16(const unsigned short* g, unsigned short* l) {
    __builtin_amdgcn_global_load_lds(
        (const __attribute__((address_space(1))) unsigned int*)g,
        (__attribute__((address_space(3))) unsigned int*)l,
        16, 0, 0);
}

__global__ __launch_bounds__(256) void gemm_kernel(
        const unsigned short* __restrict__ A,   // zn, (M, K) bf16
        const unsigned short* __restrict__ B,   // Wt, (N, K) bf16
        const float* __restrict__ bias,
        const float* __restrict__ scale,
        float* __restrict__ out) {
    __shared__ __align__(16) unsigned short As[128 * 32];
    __shared__ __align__(16) unsigned short Bs[128 * 32];

    const int tid = threadIdx.x;
    const int wave = tid >> 6, lane = tid & 63;
    const int wm = wave >> 1, wn = wave & 1;     // 2x2 wave grid, 64x64 each
    const int bn = blockIdx.x, bm = blockIdx.y;
    const int l15 = lane & 15, l4 = lane >> 4;

    // staging: wave w covers rows [32w, 32w+32) of each 128x32 tile via 2 chunks
    const int sr = lane >> 2;            // 0..15 row within 16-row chunk
    const int sc = (lane & 3) * 8;       // col (bf16 elems)
    const unsigned short* ag0 = A + (size_t)(bm * 128 + wave * 32 + sr) * K_DIM + sc;
    const unsigned short* bg0 = B + (size_t)(bn * 128 + wave * 32 + sr) * K_DIM + sc;
    unsigned short* as0 = &As[wave * 1024];
    unsigned short* bs0 = &Bs[wave * 1024];

    f32x4 acc[4][4] = {};

    for (int k0 = 0; k0 < K_DIM; k0 += 32) {
        __syncthreads();
        async_copy16(ag0 + k0, as0);
        async_copy16(ag0 + k0 + 16 * K_DIM, as0 + 512);
        async_copy16(bg0 + k0, bs0);
        async_copy16(bg0 + k0 + 16 * K_DIM, bs0 + 512);
        __syncthreads();

        bf16x8 a[4], b[4];
#pragma unroll
        for (int i = 0; i < 4; i++)
            a[i] = *(const bf16x8*)&As[(wm * 64 + i * 16 + l15) * 32 + l4 * 8];
#pragma unroll
        for (int i = 0; i < 4; i++)
            b[i] = *(const bf16x8*)&Bs[(wn * 64 + i * 16 + l15) * 32 + l4 * 8];
#pragma unroll
        for (int i = 0; i < 4; i++)
#pragma unroll
            for (int j = 0; j < 4; j++)
                acc[i][j] = __builtin_amdgcn_mfma_f32_16x16x32_bf16(a[i], b[j], acc[i][j], 0, 0, 0);
    }

    const float scl = scale[0];
#pragma unroll
    for (int j = 0; j < 4; j++) {
        const int gcol = bn * 128 + wn * 64 + j * 16 + l15;
        const float bv = bias[gcol];
#pragma unroll
        for (int i = 0; i < 4; i++) {
            const int grow = bm * 128 + wm * 64 + i * 16 + l4 * 4;
#pragma unroll
            for (int r = 0; r < 4; r++) {
                float x = (acc[i][j][r] + bv) * scl;
                float y = x * (1.0f / 3.0f);
                y = fminf(fmaxf(y, -15.f), 15.f);
                const float e = __expf(2.f * y);
                out[(size_t)(grow + r) * N_DIM + gcol] = 3.f * (e - 1.f) / (e + 1.f);
            }
        }
    }
}

extern "C" void kernel_launch(void* const* d_in, const int* in_sizes, int n_in,
                              void* d_out, int out_size, void* d_ws, size_t ws_size,
                              hipStream_t stream) {
    const float* z     = (const float*)d_in[0];
    const float* gamma = (const float*)d_in[1];
    const float* beta  = (const float*)d_in[2];
    const float* W     = (const float*)d_in[3];
    const float* b     = (const float*)d_in[4];
    const float* scale = (const float*)d_in[5];
    float* out = (float*)d_out;

    unsigned short* zn = (unsigned short*)d_ws;                 // 16384*1024 bf16 = 32 MB
    unsigned short* Wt = zn + (size_t)M_DIM * K_DIM;            // 4096*1024 bf16  =  8 MB

    ln_kernel<<<M_DIM / 4, 256, 0, stream>>>(z, gamma, beta, zn);
    tr_kernel<<<dim3(N_DIM / 32, K_DIM / 32), dim3(32, 8), 0, stream>>>(W, Wt);
    gemm_kernel<<<dim3(N_DIM / 128, M_DIM / 128), 256, 0, stream>>>(zn, Wt, b, scale, out);
}

// Round 3
// 484.371 us; speedup vs baseline: 1.0234x; 1.0234x over previous
//
#include <hip/hip_runtime.h>

// out = tanh(((LN(z) @ W + b) * scale)/3)*3
// All I/O fp32 (per reference): z (16384,1024), W (1024,4096), out (16384,4096).
// Internal: zn and Wt converted to bf16 for MFMA (no fp32 MFMA on CDNA4).
#define M_DIM 16384
#define K_DIM 1024
#define N_DIM 4096

typedef __bf16 bf16x8 __attribute__((ext_vector_type(8)));
typedef float f32x16 __attribute__((ext_vector_type(16)));

__device__ __forceinline__ unsigned short f2bf(float f) {
    union { float f; unsigned int i; } v; v.f = f;
    unsigned int r = v.i + 0x7fffu + ((v.i >> 16) & 1u);  // round-to-nearest-even
    return (unsigned short)(r >> 16);
}
__device__ __forceinline__ unsigned int pack2(float lo, float hi) {
    return ((unsigned int)f2bf(lo)) | (((unsigned int)f2bf(hi)) << 16);
}

// ---------------- LayerNorm: one wave per row of 1024, fp32 in -> bf16 out ----------------
// Fully coalesced: load v spans bytes [v*1024, v*1024+1024) contiguously across the wave.
__global__ __launch_bounds__(256) void ln_kernel(
        const float* __restrict__ z,
        const float* __restrict__ gamma,
        const float* __restrict__ beta,
        unsigned short* __restrict__ zn) {
    const int wave = threadIdx.x >> 6;
    const int lane = threadIdx.x & 63;
    const size_t row = (size_t)blockIdx.x * 4 + wave;
    const float* zr = z + row * K_DIM;

    float4 x[4];
#pragma unroll
    for (int v = 0; v < 4; v++) x[v] = *(const float4*)(zr + v * 256 + lane * 4);

    float s = 0.f, ss = 0.f;
#pragma unroll
    for (int v = 0; v < 4; v++) {
        s  += x[v].x + x[v].y + x[v].z + x[v].w;
        ss += x[v].x * x[v].x + x[v].y * x[v].y + x[v].z * x[v].z + x[v].w * x[v].w;
    }
#pragma unroll
    for (int o = 32; o; o >>= 1) { s += __shfl_xor(s, o, 64); ss += __shfl_xor(ss, o, 64); }
    const float mean = s * (1.f / K_DIM);
    const float var = ss * (1.f / K_DIM) - mean * mean;
    const float rstd = rsqrtf(var + 1e-5f);

#pragma unroll
    for (int v = 0; v < 4; v++) {
        float4 g = *(const float4*)(gamma + v * 256 + lane * 4);
        float4 b = *(const float4*)(beta + v * 256 + lane * 4);
        float o0 = (x[v].x - mean) * rstd * g.x + b.x;
        float o1 = (x[v].y - mean) * rstd * g.y + b.y;
        float o2 = (x[v].z - mean) * rstd * g.z + b.z;
        float o3 = (x[v].w - mean) * rstd * g.w + b.w;
        uint2 q; q.x = pack2(o0, o1); q.y = pack2(o2, o3);
        *(uint2*)(zn + row * K_DIM + v * 256 + lane * 4) = q;
    }
}

// ---------------- Transpose+convert W fp32 (K,N) -> Wt bf16 (N,K) ----------------
__global__ __launch_bounds__(256) void tr_kernel(
        const float* __restrict__ W, unsigned short* __restrict__ Wt) {
    __shared__ float t[32][33];
    const int tx = threadIdx.x, ty = threadIdx.y;   // block (32, 8)
    const int n0 = blockIdx.x * 32, k0 = blockIdx.y * 32;
#pragma unroll
    for (int j = 0; j < 32; j += 8)
        t[ty + j][tx] = W[(size_t)(k0 + ty + j) * N_DIM + n0 + tx];
    __syncthreads();
#pragma unroll
    for (int j = 0; j < 32; j += 8)
        Wt[(size_t)(n0 + ty + j) * K_DIM + k0 + tx] = f2bf(t[tx][ty + j]);
}

// ---------------- GEMM: zn (M,K)bf16 @ Wt (N,K)bf16, 32x32x16 MFMA, swizzled LDS ----------------
// LDS layout (per 128x32 tile): 16B-unit index of (row, chunk c in [0,4)) is
//   u = row*4 + (c ^ ((row>>1)&3))
// The XOR spreads consecutive rows across all 8 bank-groups (was 2 -> 1.7e7 conflicts).
// global_load_lds writes lane l's 16B to base + l*16, so staging lane l FETCHES
// row (l>>2), chunk ((l&3) ^ ((l>>3)&3)) to realize this layout.
__device__ __forceinline__ void async_copy16(const unsigned short* g, unsigned short* l) {
    __builtin_amdgcn_global_load_lds(
        (const __attribute__((address_space(1))) unsigned int*)g,
        (__attribute__((address_space(3))) unsigned int*)l,
        16, 0, 0);
}

__global__ __launch_bounds__(256) void gemm_kernel(
        const unsigned short* __restrict__ A,   // zn, (M, K) bf16
        const unsigned short* __restrict__ B,   // Wt, (N, K) bf16
        const float* __restrict__ bias,
        const float* __restrict__ scale,
        float* __restrict__ out) {
    __shared__ __align__(16) unsigned short As[128 * 32];
    __shared__ __align__(16) unsigned short Bs[128 * 32];

    const int tid = threadIdx.x;
    const int wave = tid >> 6, lane = tid & 63;
    const int wm = wave >> 1, wn = wave & 1;     // 2x2 wave grid, 64x64 each
    const int bn = blockIdx.x, bm = blockIdx.y;
    const int l31 = lane & 31, lhi = lane >> 5;

    // staging: wave w covers rows [32w, 32w+32) of each 128x32 tile via 2 chunks of 16 rows
    const int sr = lane >> 2;                                  // row within 16-row chunk
    const int sc = ((lane & 3) ^ ((lane >> 3) & 3)) * 8;       // swizzled k-chunk (bf16 elems)
    const unsigned short* ag0 = A + (size_t)(bm * 128 + wave * 32 + sr) * K_DIM + sc;
    const unsigned short* bg0 = B + (size_t)(bn * 128 + wave * 32 + sr) * K_DIM + sc;
    unsigned short* as0 = &As[wave * 1024];
    unsigned short* bs0 = &Bs[wave * 1024];

    f32x16 acc[2][2] = {};

    const int swz = (l31 >> 1) & 3;   // row-dependent XOR for fragment reads

    for (int k0 = 0; k0 < K_DIM; k0 += 32) {
        __syncthreads();
        async_copy16(ag0 + k0, as0);
        async_copy16(ag0 + k0 + 16 * K_DIM, as0 + 512);
        async_copy16(bg0 + k0, bs0);
        async_copy16(bg0 + k0 + 16 * K_DIM, bs0 + 512);
        __syncthreads();

#pragma unroll
        for (int s = 0; s < 2; s++) {
            const int c = s * 2 + lhi;       // k-chunk 0..3
            bf16x8 a[2], b[2];
#pragma unroll
            for (int i = 0; i < 2; i++)
                a[i] = *(const bf16x8*)&As[(wm * 64 + i * 32 + l31) * 32 + (c ^ swz) * 8];
#pragma unroll
            for (int j = 0; j < 2; j++)
                b[j] = *(const bf16x8*)&Bs[(wn * 64 + j * 32 + l31) * 32 + (c ^ swz) * 8];
#pragma unroll
            for (int i = 0; i < 2; i++)
#pragma unroll
                for (int j = 0; j < 2; j++)
                    acc[i][j] = __builtin_amdgcn_mfma_f32_32x32x16_bf16(a[i], b[j], acc[i][j], 0, 0, 0);
        }
    }

    // Epilogue: out = 3*tanh(x/3) = 3 - 6/(exp2(x*2/(3 ln2)) + 1); saturates correctly at +-inf.
    const float mfac = scale[0] * 0.96179669392236f;   // scale * 2/(3*ln2)
#pragma unroll
    for (int j = 0; j < 2; j++) {
        const int gcol = bn * 128 + wn * 64 + j * 32 + l31;
        const float bv = bias[gcol];
#pragma unroll
        for (int i = 0; i < 2; i++) {
            const int rbase = bm * 128 + wm * 64 + i * 32 + 4 * lhi;
#pragma unroll
            for (int r = 0; r < 16; r++) {
                const int grow = rbase + (r & 3) + 8 * (r >> 2);
                float t = (acc[i][j][r] + bv) * mfac;
                float e = __builtin_amdgcn_exp2f(t);
                out[(size_t)grow * N_DIM + gcol] = 3.f - 6.f * __builtin_amdgcn_rcpf(e + 1.f);
            }
        }
    }
}

extern "C" void kernel_launch(void* const* d_in, const int* in_sizes, int n_in,
                              void* d_out, int out_size, void* d_ws, size_t ws_size,
                              hipStream_t stream) {
    const float* z     = (const float*)d_in[0];
    const float* gamma = (const float*)d_in[1];
    const float* beta  = (const float*)d_in[2];
    const float* W     = (const float*)d_in[3];
    const float* b     = (const float*)d_in[4];
    const float* scale = (const float*)d_in[5];
    float* out = (float*)d_out;

    unsigned short* zn = (unsigned short*)d_ws;                 // 16384*1024 bf16 = 32 MB
    unsigned short* Wt = zn + (size_t)M_DIM * K_DIM;            // 4096*1024 bf16  =  8 MB

    ln_kernel<<<M_DIM / 4, 256, 0, stream>>>(z, gamma, beta, zn);
    tr_kernel<<<dim3(N_DIM / 32, K_DIM / 32), dim3(32, 8), 0, stream>>>(W, Wt);
    gemm_kernel<<<dim3(N_DIM / 128, M_DIM / 128), 256, 0, stream>>>(zn, Wt, b, scale, out);
}